// Round 1
// baseline (216.288 us; speedup 1.0000x reference)
//
#include <hip/hip_runtime.h>
#include <math.h>

#define NC 1000          // NUM_CLASSES
#define NV 250           // float4 chunks per row (1000/4)

__device__ __forceinline__ float sigmoidf(float x) {
    return 1.0f / (1.0f + expf(-x));
}

__global__ __launch_bounds__(256)
void smooth_filter_kernel(const float* __restrict__ in, float* __restrict__ out) {
    const int row  = blockIdx.x;
    const int t    = threadIdx.x;
    const int wave = t >> 6;
    const int lane = t & 63;

    const float4* __restrict__ rp = (const float4*)(in + (size_t)row * NC);

    float4 v = make_float4(0.f, 0.f, 0.f, 0.f);
    if (t < NV) v = rp[t];

    const float a0 = fabsf(v.x), a1 = fabsf(v.y), a2 = fabsf(v.z), a3 = fabsf(v.w);

    float s_r  = (v.x + v.y) + (v.z + v.w);          // sum(r)
    float s_a  = (a0 + a1) + (a2 + a3);              // sum(|r|)
    float s_a2 = (a0 * a0 + a1 * a1) + (a2 * a2 + a3 * a3); // sum(|r|^2)

    // wave-64 butterfly-ish shuffle reduction
    #pragma unroll
    for (int off = 32; off > 0; off >>= 1) {
        s_r  += __shfl_down(s_r,  off, 64);
        s_a  += __shfl_down(s_a,  off, 64);
        s_a2 += __shfl_down(s_a2, off, 64);
    }

    __shared__ float red[3][4];
    if (lane == 0) {
        red[0][wave] = s_r;
        red[1][wave] = s_a;
        red[2][wave] = s_a2;
    }
    __syncthreads();

    const float S   = (red[0][0] + red[0][1]) + (red[0][2] + red[0][3]);
    const float SA  = (red[1][0] + red[1][1]) + (red[1][2] + red[1][3]);
    const float SA2 = (red[2][0] + red[2][1]) + (red[2][2] + red[2][3]);

    const float mean    = SA * (1.0f / NC);
    // unbiased variance: (sum(a^2) - n*mean^2) / (n-1)
    const float var     = (SA2 - (float)NC * mean * mean) * (1.0f / (NC - 1));
    const float inv_std = rsqrtf(var);
    const float c       = 1.0f / (NC - 1);

    if (t < NV) {
        float4 o;
        o.x = v.x + sigmoidf((a0 - mean) * inv_std) * c * (S - (float)NC * v.x);
        o.y = v.y + sigmoidf((a1 - mean) * inv_std) * c * (S - (float)NC * v.y);
        o.z = v.z + sigmoidf((a2 - mean) * inv_std) * c * (S - (float)NC * v.z);
        o.w = v.w + sigmoidf((a3 - mean) * inv_std) * c * (S - (float)NC * v.w);
        ((float4*)(out + (size_t)row * NC))[t] = o;
    }
}

extern "C" void kernel_launch(void* const* d_in, const int* in_sizes, int n_in,
                              void* d_out, int out_size, void* d_ws, size_t ws_size,
                              hipStream_t stream) {
    const float* in  = (const float*)d_in[0];
    float*       out = (float*)d_out;
    const int rows   = in_sizes[0] / NC;   // 32768
    smooth_filter_kernel<<<rows, 256, 0, stream>>>(in, out);
}